// Round 7
// baseline (60.185 us; speedup 1.0000x reference)
//
#include <hip/hip_runtime.h>

// Problem constants (from reference setup_inputs): N=64, D=64, S=64, m=128
constexpr int N_ = 64;
constexpr int D_ = 64;
constexpr int S_ = 64;
constexpr int M_ = 128;

typedef float fv4 __attribute__((ext_vector_type(4)));

// out[n,s,i,j] = t4[n,s,i] + t3[n,s,j] + (t1[n,s,i] + t2[n,s]) * (i==j)
//             + t5[n,s] + bias[s]
// One block per (n,s). Write-bound: 256 MiB fp32 output.
// R3 structure (best: 48.6 us) + nontemporal stores (A/B vs regular).
// Static vector-component indexing ONLY in the store loop (rule #20).
__global__ __launch_bounds__(256) void l12_fused(
    const float* __restrict__ x,       // [N, D, M]
    const float* __restrict__ coeffs,  // [D, S, 5]
    const float* __restrict__ bias,    // [S] (shape (1,S,1,1) flattened)
    float* __restrict__ out)           // [N, S, M, M]
{
    const int blk = blockIdx.x;        // n*S + s
    const int n   = blk >> 6;          // / S_
    const int s   = blk & (S_ - 1);
    const int t   = threadIdx.x;       // 0..255
    const int i   = t & (M_ - 1);      // 0..127
    const int half = t >> 7;           // 0 or 1 (D-split)

    __shared__ float sh_c[D_][5];
    __shared__ float part[5][2][M_];
    __shared__ __align__(16) float A3[M_];   // row-addend t3[j]
    __shared__ float CB[M_];                 // col-addend t4[i] + t5 + bias
    __shared__ float DG[M_];                 // t1[i] + t2
    __shared__ float wred[4];

    // Stage coeffs for this s: 64 d-rows x 5
    if (t < D_) {
        const float* cp = coeffs + (t * S_ + s) * 5;
        #pragma unroll
        for (int k = 0; k < 5; ++k) sh_c[t][k] = cp[k];
    }
    __syncthreads();

    // Five contractions over D, split 2-way across threads.
    float r0 = 0.f, r1 = 0.f, r2 = 0.f, r3 = 0.f, r4 = 0.f;
    const float* xp = x + ((size_t)(n * D_) + half * (D_ / 2)) * M_ + i;
    #pragma unroll
    for (int dd = 0; dd < D_ / 2; ++dd) {
        float xv = xp[(size_t)dd * M_];   // coalesced across i, L2-resident
        int d = half * (D_ / 2) + dd;
        r0 += sh_c[d][0] * xv;
        r1 += sh_c[d][1] * xv;
        r2 += sh_c[d][2] * xv;
        r3 += sh_c[d][3] * xv;
        r4 += sh_c[d][4] * xv;
    }
    part[0][half][i] = r0;
    part[1][half][i] = r1;
    part[2][half][i] = r2;
    part[3][half][i] = r3;
    part[4][half][i] = r4;
    __syncthreads();

    if (t < M_) {
        float a1 = part[0][0][i] + part[0][1][i];
        float a2 = part[1][0][i] + part[1][1][i];
        float a3 = part[2][0][i] + part[2][1][i];
        float a4 = part[3][0][i] + part[3][1][i];
        float a5 = part[4][0][i] + part[4][1][i];
        A3[i] = a3;
        DG[i] = a1;    // + t2 added after reduction
        CB[i] = a4;    // + (t5 + bias) added after reduction

        float v2 = a2, v5 = a5;
        #pragma unroll
        for (int off = 32; off; off >>= 1) {
            v2 += __shfl_down(v2, off);
            v5 += __shfl_down(v5, off);
        }
        if ((t & 63) == 0) {
            wred[(t >> 6) * 2 + 0] = v2;
            wred[(t >> 6) * 2 + 1] = v5;
        }
    }
    __syncthreads();

    if (t < M_) {
        const float inv_m = 1.0f / (float)M_;
        DG[i] += (wred[0] + wred[2]) * inv_m;
        CB[i] += (wred[1] + wred[3]) * inv_m + bias[s];
    }
    __syncthreads();

    // Write the 128x128 tile, fully coalesced fv4 NT stores.
    fv4* outp = reinterpret_cast<fv4*>(out + (size_t)blk * (M_ * M_));
    const int j4 = (t & 31) * 4;
    const fv4 a3v = *reinterpret_cast<const fv4*>(&A3[j4]);

    #pragma unroll
    for (int it = 0; it < 16; ++it) {
        int l   = it * 256 + t;      // fv4 index within tile (0..4095)
        int row = l >> 5;            // 32 fv4 per row
        float base = CB[row];        // 2-way LDS broadcast (free)
        float dg   = DG[row];
        fv4 v;
        v.x = base + a3v.x + ((row == j4 + 0) ? dg : 0.f);
        v.y = base + a3v.y + ((row == j4 + 1) ? dg : 0.f);
        v.z = base + a3v.z + ((row == j4 + 2) ? dg : 0.f);
        v.w = base + a3v.w + ((row == j4 + 3) ? dg : 0.f);
        __builtin_nontemporal_store(v, &outp[l]);   // evict-first write stream
    }
}

extern "C" void kernel_launch(void* const* d_in, const int* in_sizes, int n_in,
                              void* d_out, int out_size, void* d_ws, size_t ws_size,
                              hipStream_t stream) {
    const float* x      = (const float*)d_in[0];  // [64,64,128]
    const float* coeffs = (const float*)d_in[1];  // [64,64,5]
    const float* bias   = (const float*)d_in[2];  // [1,64,1,1] -> 64
    float* out          = (float*)d_out;          // [64,64,128,128]

    l12_fused<<<dim3(N_ * S_), dim3(256), 0, stream>>>(x, coeffs, bias, out);
}

// Round 8
// 48.411 us; speedup vs baseline: 1.2432x; 1.2432x over previous
//
#include <hip/hip_runtime.h>

// Problem constants (from reference setup_inputs): N=64, D=64, S=64, m=128
constexpr int N_ = 64;
constexpr int D_ = 64;
constexpr int S_ = 64;
constexpr int M_ = 128;

typedef float fv4 __attribute__((ext_vector_type(4)));

// out[n,s,i,j] = t4[n,s,i] + t3[n,s,j] + (t1[n,s,i] + t2[n,s]) * (i==j)
//             + t5[n,s] + bias[s]
// One block per (n,s). Write-bound: 256 MiB fp32 output.
// Best-known configuration (R3: 48.6 us ≈ 6.2 TB/s effective store stream).
// Ablation history: kernel-split (R2,R4: +5 us/launch), s-pairing (R5: worse),
// two-tile drain overlap (R6: +1 us), NT stores (R7: −24%). All reverted.
// Static vector-component indexing ONLY in the store loop (rule #20 —
// a runtime v[dj] demotes the vector to scratch and cost ~16 us in R1).
__global__ __launch_bounds__(256) void l12_fused(
    const float* __restrict__ x,       // [N, D, M]
    const float* __restrict__ coeffs,  // [D, S, 5]
    const float* __restrict__ bias,    // [S] (shape (1,S,1,1) flattened)
    float* __restrict__ out)           // [N, S, M, M]
{
    const int blk = blockIdx.x;        // n*S + s
    const int n   = blk >> 6;          // / S_
    const int s   = blk & (S_ - 1);
    const int t   = threadIdx.x;       // 0..255
    const int i   = t & (M_ - 1);      // 0..127
    const int half = t >> 7;           // 0 or 1 (D-split)

    __shared__ float sh_c[D_][5];
    __shared__ float part[5][2][M_];
    __shared__ __align__(16) float A3[M_];   // row-addend t3[j]
    __shared__ float CB[M_];                 // col-addend t4[i] + t5 + bias
    __shared__ float DG[M_];                 // t1[i] + t2
    __shared__ float wred[4];

    // Stage coeffs for this s: 64 d-rows x 5
    if (t < D_) {
        const float* cp = coeffs + (t * S_ + s) * 5;
        #pragma unroll
        for (int k = 0; k < 5; ++k) sh_c[t][k] = cp[k];
    }
    __syncthreads();

    // Five contractions over D, split 2-way across threads.
    float r0 = 0.f, r1 = 0.f, r2 = 0.f, r3 = 0.f, r4 = 0.f;
    const float* xp = x + ((size_t)(n * D_) + half * (D_ / 2)) * M_ + i;
    #pragma unroll
    for (int dd = 0; dd < D_ / 2; ++dd) {
        float xv = xp[(size_t)dd * M_];   // coalesced across i, L2-resident
        int d = half * (D_ / 2) + dd;
        r0 += sh_c[d][0] * xv;
        r1 += sh_c[d][1] * xv;
        r2 += sh_c[d][2] * xv;
        r3 += sh_c[d][3] * xv;
        r4 += sh_c[d][4] * xv;
    }
    part[0][half][i] = r0;
    part[1][half][i] = r1;
    part[2][half][i] = r2;
    part[3][half][i] = r3;
    part[4][half][i] = r4;
    __syncthreads();

    if (t < M_) {
        float a1 = part[0][0][i] + part[0][1][i];
        float a2 = part[1][0][i] + part[1][1][i];
        float a3 = part[2][0][i] + part[2][1][i];
        float a4 = part[3][0][i] + part[3][1][i];
        float a5 = part[4][0][i] + part[4][1][i];
        A3[i] = a3;
        DG[i] = a1;    // + t2 added after reduction
        CB[i] = a4;    // + (t5 + bias) added after reduction

        float v2 = a2, v5 = a5;
        #pragma unroll
        for (int off = 32; off; off >>= 1) {
            v2 += __shfl_down(v2, off);
            v5 += __shfl_down(v5, off);
        }
        if ((t & 63) == 0) {
            wred[(t >> 6) * 2 + 0] = v2;
            wred[(t >> 6) * 2 + 1] = v5;
        }
    }
    __syncthreads();

    if (t < M_) {
        const float inv_m = 1.0f / (float)M_;
        DG[i] += (wred[0] + wred[2]) * inv_m;
        CB[i] += (wred[1] + wred[3]) * inv_m + bias[s];
    }
    __syncthreads();

    // Write the 128x128 tile, fully coalesced fv4 stores.
    fv4* outp = reinterpret_cast<fv4*>(out + (size_t)blk * (M_ * M_));
    const int j4 = (t & 31) * 4;
    const fv4 a3v = *reinterpret_cast<const fv4*>(&A3[j4]);

    #pragma unroll
    for (int it = 0; it < 16; ++it) {
        int l   = it * 256 + t;      // fv4 index within tile (0..4095)
        int row = l >> 5;            // 32 fv4 per row
        float base = CB[row];        // 2-way LDS broadcast (free)
        float dg   = DG[row];
        fv4 v;
        v.x = base + a3v.x + ((row == j4 + 0) ? dg : 0.f);
        v.y = base + a3v.y + ((row == j4 + 1) ? dg : 0.f);
        v.z = base + a3v.z + ((row == j4 + 2) ? dg : 0.f);
        v.w = base + a3v.w + ((row == j4 + 3) ? dg : 0.f);
        outp[l] = v;                 // static indexing only — stays in VGPRs
    }
}

extern "C" void kernel_launch(void* const* d_in, const int* in_sizes, int n_in,
                              void* d_out, int out_size, void* d_ws, size_t ws_size,
                              hipStream_t stream) {
    const float* x      = (const float*)d_in[0];  // [64,64,128]
    const float* coeffs = (const float*)d_in[1];  // [64,64,5]
    const float* bias   = (const float*)d_in[2];  // [1,64,1,1] -> 64
    float* out          = (float*)d_out;          // [64,64,128,128]

    l12_fused<<<dim3(N_ * S_), dim3(256), 0, stream>>>(x, coeffs, bias, out);
}